// Round 15
// baseline (839.584 us; speedup 1.0000x reference)
//
#include <hip/hip_runtime.h>

// SpikeLinear: out = LIF_scan( x @ W^T + bias ) over T=8 timesteps.
//
// Numerics (DO NOT CHANGE): must reproduce numpy/OpenBLAS sgemm bit-for-bit
// because the spike threshold (memb > 1.0) is discontinuous. OpenBLAS
// accumulates each C element as a strict sequential fp32 FMA chain over
// ascending k, blocked by kc=384: each panel accumulates from zero in
// registers, then C += panel (fp32 add) in ascending panel order, then fp32
// bias add and fp32 LIF scan. Verified absmax == 0.0 in rounds 3, 8-14.
//
// Perf lineage:
//  r13: staging-bank fix + prefetch, (256,2) -> 800us total, 381us/slice.
//  r14: (256,4) -> occupancy UNCHANGED (bound only caps the allocator),
//       -5%. LDS-pipe budget for the 8x8 tile: 4 b128 reads per 16 MACs
//       -> ~338us of the 381us wall = LDS-read-pipe saturated.
//  r15 (this): 8x16 register tile (TILE_NP=512): 6 b128 reads per 128 MACs
//       (21.3 MACs/read, -25% LDS insts/MAC). 128 acc floats + ~70 working
//       needs ~200 VGPR -> __launch_bounds__(256,1) (512-reg cap; the
//       r4/r5 spills were the (256,2) 128-cap, not the tile size).

typedef float v2f __attribute__((ext_vector_type(2)));

// acc = x.word0 * w + acc   (x broadcast from word0 of the pair)
#define PK_LO(a, x, wv)                                                       \
    asm("v_pk_fma_f32 %0, %1, %2, %0 op_sel:[0,0,0] op_sel_hi:[0,1,1]"        \
        : "+v"(a) : "v"(x), "v"(wv))
// acc = x.word1 * w + acc   (x broadcast from word1 of the pair)
#define PK_HI(a, x, wv)                                                       \
    asm("v_pk_fma_f32 %0, %1, %2, %0 op_sel:[1,0,0] op_sel_hi:[1,1,1]"        \
        : "+v"(a) : "v"(x), "v"(wv))

constexpr int TSTEPS = 8;
constexpr int BK     = 16;
constexpr int TILE_M = 64;    // 8 batches * 8 timesteps
constexpr int TILE_NP= 512;   // panel-kernel tile: 4 waves x 128 cols
constexpr int TILE_N = 128;   // fallback-kernel tile
constexpr int KC     = 384;   // OpenBLAS SGEMM_DEFAULT_Q on x86-64
constexpr int WS_PAD = 4;     // wsh row stride 516 == 4 mod 32 (bank spread)

// ---------------------------------------------------------------- phase 1 --
__global__ __launch_bounds__(256, 1)
void spike_panel_gemm(const float* __restrict__ x,
                      const float* __restrict__ w,
                      float* __restrict__ panels,   // ws: panels 0..np-2, NW cols
                      float* __restrict__ out,      // last panel, spike layout
                      int slice0, int NW,
                      int B, int IN, int OUT, int npanels)
{
    __shared__ float xs[BK][TILE_M + 4];
    __shared__ float wsh[BK][TILE_NP + WS_PAD];

    const int tid  = threadIdx.x;
    const int lane = tid & 63;
    const int wv   = tid >> 6;       // wave 0..3 -> col strip [128w, 128w+128)
    const int rg   = lane >> 3;      // row octet 0..7 -> batch within tile
    const int cg   = lane & 7;       // col quad index
    const int clo  = wv * 128 + cg * 4;  // cols clo + {0..3, 32..35, 64..67, 96..99}

    const int m0 = blockIdx.y * TILE_M;
    const int n0 = slice0 + blockIdx.x * TILE_NP;
    const int p  = blockIdx.z;
    const int ks = p * KC;
    const int ke = (ks + KC < IN) ? (ks + KC) : IN;

    // acc[t][qq]: col = clo + 32*(qq>>1) + 2*(qq&1) + component
    v2f acc[TSTEPS][8];
    #pragma unroll
    for (int t = 0; t < TSTEPS; ++t)
        #pragma unroll
        for (int q = 0; q < 8; ++q) acc[t][q] = (v2f){0.f, 0.f};

    const int sr = tid >> 2;         // 0..63
    const int sk = (tid & 3) * 4;    // 0,4,8,12

    const float* xrow = x + (size_t)(m0 + sr) * IN + sk;
    const float* wrow[8];
    #pragma unroll
    for (int g = 0; g < 8; ++g)
        wrow[g] = w + (size_t)(n0 + g * 64 + sr) * IN + sk;

    const int nsteps = (ke - ks) / BK;

    // prologue: load step 0 into prefetch registers
    float4 xv = *(const float4*)(xrow + ks);
    float4 wvp[8];
    #pragma unroll
    for (int g = 0; g < 8; ++g) wvp[g] = *(const float4*)(wrow[g] + ks);

    for (int s = 0; s < nsteps; ++s) {
        __syncthreads();
        xs[sk+0][sr] = xv.x;  xs[sk+1][sr] = xv.y;
        xs[sk+2][sr] = xv.z;  xs[sk+3][sr] = xv.w;
        #pragma unroll
        for (int g = 0; g < 8; ++g) {
            wsh[sk+0][sr + g*64] = wvp[g].x;
            wsh[sk+1][sr + g*64] = wvp[g].y;
            wsh[sk+2][sr + g*64] = wvp[g].z;
            wsh[sk+3][sr + g*64] = wvp[g].w;
        }
        __syncthreads();

        // prefetch step s+1: latency hides under the 32-k-eq FMA block below
        if (s + 1 < nsteps) {
            const int ko = ks + (s + 1) * BK;
            xv = *(const float4*)(xrow + ko);
            #pragma unroll
            for (int g = 0; g < 8; ++g)
                wvp[g] = *(const float4*)(wrow[g] + ko);
        }

        #pragma unroll
        for (int k = 0; k < BK; ++k) {
            // xp[tp] = {x[2tp], x[2tp+1]} for this thread's batch row
            v2f xp[4], wva[8];
            *(float4*)&xp[0]  = *(const float4*)&xs[k][rg*8];
            *(float4*)&xp[2]  = *(const float4*)&xs[k][rg*8 + 4];
            *(float4*)&wva[0] = *(const float4*)&wsh[k][clo];
            *(float4*)&wva[2] = *(const float4*)&wsh[k][clo + 32];
            *(float4*)&wva[4] = *(const float4*)&wsh[k][clo + 64];
            *(float4*)&wva[6] = *(const float4*)&wsh[k][clo + 96];
            #pragma unroll
            for (int tp = 0; tp < 4; ++tp) {
                #pragma unroll
                for (int q = 0; q < 8; ++q) {
                    PK_LO(acc[2*tp  ][q], xp[tp], wva[q]);
                    PK_HI(acc[2*tp+1][q], xp[tp], wva[q]);
                }
            }
        }
    }

    const int bg = blockIdx.y * 8 + rg;            // global batch index
    const int cs = blockIdx.x * TILE_NP + clo;     // col within slice
    if (p < npanels - 1) {
        // panels 0..np-2: m-major rows (b*8 + t), NW-wide, slot p in ws
        float* pb = panels + ((size_t)p * B * TSTEPS) * NW;
        #pragma unroll
        for (int t = 0; t < TSTEPS; ++t) {
            const int m = bg * TSTEPS + t;
            float* dst = pb + (size_t)m * NW + cs;
            #pragma unroll
            for (int b32 = 0; b32 < 4; ++b32) {
                float4 v4;
                *(v2f*)&v4.x = acc[t][2*b32];
                *(v2f*)&v4.z = acc[t][2*b32 + 1];
                *(float4*)(dst + 32*b32) = v4;
            }
        }
    } else {
        // last panel -> out with SPIKE row mapping (t*B + b): phase 2's
        // reader thread == writer thread (no cross-thread hazard).
        const int o0 = n0 + clo;
        #pragma unroll
        for (int t = 0; t < TSTEPS; ++t) {
            float* op = out + ((size_t)t * B + bg) * OUT + o0;
            #pragma unroll
            for (int b32 = 0; b32 < 4; ++b32) {
                float4 v4;
                *(v2f*)&v4.x = acc[t][2*b32];
                *(v2f*)&v4.z = acc[t][2*b32 + 1];
                *(float4*)(op + 32*b32) = v4;
            }
        }
    }
}

// ---------------------------------------------------------------- phase 2 --
__global__ __launch_bounds__(256)
void spike_fold_scan(const float* __restrict__ panels,
                     const float* __restrict__ bias,
                     float* __restrict__ out,
                     int slice0, int NW,
                     int B, int OUT, int npanels)
{
    const int b = blockIdx.y;
    const size_t psz = (size_t)B * TSTEPS * NW;
    const int nc4 = NW / 4;

    for (int c4 = blockIdx.x * 256 + threadIdx.x; c4 < nc4;
         c4 += gridDim.x * 256) {
        const int cs   = c4 * 4;          // col within slice
        const int gcol = slice0 + cs;     // global col

        // v = panel0; v += panel1 ... += panel(np-2)  (exact BLAS order)
        float4 v[TSTEPS];
        #pragma unroll
        for (int t = 0; t < TSTEPS; ++t)
            v[t] = *(const float4*)(panels + (size_t)(b*TSTEPS + t) * NW + cs);
        for (int p = 1; p < npanels - 1; ++p) {
            const float* pb = panels + (size_t)p * psz;
            #pragma unroll
            for (int t = 0; t < TSTEPS; ++t) {
                const float4 u = *(const float4*)(pb + (size_t)(b*TSTEPS + t) * NW + cs);
                v[t].x += u.x; v[t].y += u.y; v[t].z += u.z; v[t].w += u.w;
            }
        }
        // last panel from out (spike layout, owned by this thread)
        #pragma unroll
        for (int t = 0; t < TSTEPS; ++t) {
            const float4 u = *(const float4*)(out + ((size_t)t * B + b) * OUT + gcol);
            v[t].x += u.x; v[t].y += u.y; v[t].z += u.z; v[t].w += u.w;
        }

        const float4 bb = *(const float4*)(bias + gcol);
        float memb[4] = {0.f, 0.f, 0.f, 0.f};
        #pragma unroll
        for (int t = 0; t < TSTEPS; ++t) {
            float pre[4] = {v[t].x + bb.x, v[t].y + bb.y,
                            v[t].z + bb.z, v[t].w + bb.w};
            float4 sp;
            float* spp = (float*)&sp;
            #pragma unroll
            for (int c = 0; c < 4; ++c) {
                memb[c] += pre[c];                       // VTHR = 1.0 (exact)
                float s = (memb[c] > 1.0f) ? 1.0f : 0.0f;
                memb[c] *= (1.0f - s);                   // reset to zero
                spp[c] = s;
            }
            *(float4*)(out + ((size_t)t * B + b) * OUT + gcol) = sp;
        }
    }
}

// ------------------------------------------------- fallback: r3 (verified) --
__global__ __launch_bounds__(256, 4)
void spike_linear_f32seq(const float* __restrict__ x,
                         const float* __restrict__ w,
                         const float* __restrict__ bias,
                         float* __restrict__ out,
                         int B, int IN, int OUT)
{
    __shared__ float xs[BK][TILE_M + 4];
    __shared__ float ws[BK][TILE_N + 4];

    const int tid = threadIdx.x;
    const int tx  = tid & 31;
    const int ty  = tid >> 5;

    const int m0 = blockIdx.y * TILE_M;
    const int n0 = blockIdx.x * TILE_N;

    float acc_tot[TSTEPS][4];
    float acc_blk[TSTEPS][4];
    #pragma unroll
    for (int t = 0; t < TSTEPS; ++t)
        #pragma unroll
        for (int c = 0; c < 4; ++c) { acc_tot[t][c] = 0.f; acc_blk[t][c] = 0.f; }

    const int sr = tid >> 2;
    const int sk = (tid & 3) * 4;

    const float* xrow  = x + (size_t)(m0 + sr) * IN + sk;
    const float* wrow0 = w + (size_t)(n0 + sr) * IN + sk;
    const float* wrow1 = w + (size_t)(n0 + 64 + sr) * IN + sk;

    for (int kk = 0; kk < IN; kk += BK) {
        if (kk > 0 && (kk % KC) == 0) {
            #pragma unroll
            for (int t = 0; t < TSTEPS; ++t)
                #pragma unroll
                for (int c = 0; c < 4; ++c) {
                    acc_tot[t][c] += acc_blk[t][c];
                    acc_blk[t][c] = 0.f;
                }
        }
        const float4 xv  = *(const float4*)(xrow  + kk);
        const float4 wv0 = *(const float4*)(wrow0 + kk);
        const float4 wv1 = *(const float4*)(wrow1 + kk);
        __syncthreads();
        xs[sk+0][sr] = xv.x;  xs[sk+1][sr] = xv.y;
        xs[sk+2][sr] = xv.z;  xs[sk+3][sr] = xv.w;
        ws[sk+0][sr]    = wv0.x; ws[sk+1][sr]    = wv0.y;
        ws[sk+2][sr]    = wv0.z; ws[sk+3][sr]    = wv0.w;
        ws[sk+0][sr+64] = wv1.x; ws[sk+1][sr+64] = wv1.y;
        ws[sk+2][sr+64] = wv1.z; ws[sk+3][sr+64] = wv1.w;
        __syncthreads();

        #pragma unroll
        for (int k = 0; k < BK; ++k) {
            float xr[TSTEPS];
            *(float4*)&xr[0] = *(const float4*)&xs[k][ty*8];
            *(float4*)&xr[4] = *(const float4*)&xs[k][ty*8 + 4];
            float wr[4];
            *(float4*)&wr[0] = *(const float4*)&ws[k][tx*4];
            #pragma unroll
            for (int t = 0; t < TSTEPS; ++t)
                #pragma unroll
                for (int c = 0; c < 4; ++c)
                    acc_blk[t][c] = fmaf(xr[t], wr[c], acc_blk[t][c]);
        }
    }
    #pragma unroll
    for (int t = 0; t < TSTEPS; ++t)
        #pragma unroll
        for (int c = 0; c < 4; ++c)
            acc_tot[t][c] += acc_blk[t][c];

    const int bg = blockIdx.y * 8 + ty;
    const int o0 = n0 + tx * 4;
    const float4 bv = *(const float4*)(bias + o0);
    const float bb[4] = {bv.x, bv.y, bv.z, bv.w};
    float memb[4] = {0.f, 0.f, 0.f, 0.f};
    #pragma unroll
    for (int t = 0; t < TSTEPS; ++t) {
        float4 sp;
        float* spp = (float*)&sp;
        #pragma unroll
        for (int c = 0; c < 4; ++c) {
            float pre = acc_tot[t][c] + bb[c];
            memb[c] += pre;
            float s = (memb[c] > 1.0f) ? 1.0f : 0.0f;
            memb[c] *= (1.0f - s);
            spp[c] = s;
        }
        *(float4*)(out + ((size_t)t * B + bg) * OUT + o0) = sp;
    }
}

extern "C" void kernel_launch(void* const* d_in, const int* in_sizes, int n_in,
                              void* d_out, int out_size, void* d_ws, size_t ws_size,
                              hipStream_t stream)
{
    const float* x    = (const float*)d_in[0];
    const float* w    = (const float*)d_in[1];
    const float* bias = (const float*)d_in[2];
    float* out = (float*)d_out;

    const int OUT = in_sizes[2];            // 4096
    const int IN  = in_sizes[1] / OUT;      // 4096
    const int BT  = in_sizes[0] / IN;       // 2048
    const int B   = BT / TSTEPS;            // 256

    const int npanels = (IN + KC - 1) / KC; // 11

    // pick the widest column slice whose panel storage fits ws
    int NW = 0;
    for (int cand = 4096; cand >= 512; cand >>= 1) {
        if ((OUT % cand) == 0 &&
            (size_t)(npanels - 1) * BT * cand * sizeof(float) <= ws_size) {
            NW = cand;
            break;
        }
    }

    if (NW >= 512 && npanels >= 2) {
        float* panels = (float*)d_ws;
        const int nslices = OUT / NW;
        for (int s = 0; s < nslices; ++s) {
            const int slice0 = s * NW;
            dim3 g1(NW / TILE_NP, BT / TILE_M, npanels);
            spike_panel_gemm<<<g1, 256, 0, stream>>>(x, w, panels, out,
                                                     slice0, NW, B, IN, OUT,
                                                     npanels);
            int gx = NW / 1024; if (gx < 1) gx = 1;
            dim3 g2(gx, B);
            spike_fold_scan<<<g2, 256, 0, stream>>>(panels, bias, out,
                                                    slice0, NW, B, OUT,
                                                    npanels);
        }
    } else {
        dim3 grid(OUT / TILE_N, BT / TILE_M);          // (32, 32)
        spike_linear_f32seq<<<grid, 256, 0, stream>>>(x, w, bias, out, B, IN, OUT);
    }
}

// Round 16
// 809.326 us; speedup vs baseline: 1.0374x; 1.0374x over previous
//
#include <hip/hip_runtime.h>

// SpikeLinear: out = LIF_scan( x @ W^T + bias ) over T=8 timesteps.
//
// Numerics (DO NOT CHANGE): must reproduce numpy/OpenBLAS sgemm bit-for-bit
// because the spike threshold (memb > 1.0) is discontinuous. OpenBLAS
// accumulates each C element as a strict sequential fp32 FMA chain over
// ascending k, blocked by kc=384: each panel accumulates from zero in
// registers, then C += panel (fp32 add) in ascending panel order, then fp32
// bias add and fp32 LIF scan. Verified absmax == 0.0 in rounds 3, 8-15.
//
// Perf lineage:
//  r13 (best, 800us total / 381us/slice): 8x8 tile, k-major LDS, reg-staged,
//    2 barriers/step. Decomposition: 218us pk-FMA floor + ~68us staging VALU
//    + ~95us barrier/latency idle. r14 (launch-bounds) null; r15 (8x16) null
//    via occupancy collapse.
//  r16 (this): W staging via global_load_lds DMA (4 issues/wave/step replaces
//    16 ds_writes + 4 global loads + 16 prefetch regs); W LDS layout becomes
//    k-chunked [col][quarter] with SOURCE k-quarter pre-swizzled by (c>>2)&3
//    (linear DMA dest cannot be padded; swizzle on both sides, m173).
//    pk pairing flips to t-pairs: acc v2f = {t_even, t_odd}, x pairs natural
//    from k-major xs, W broadcast via op_sel. Chains stay single ascending-k
//    fmaf per (t,c) -- bit-identical. ONE barrier per step.

typedef float v2f __attribute__((ext_vector_type(2)));

// a += bcast(w2.lo) * xp   (per-component IEEE fma)
#define PK_LO(a, w2, xp)                                                      \
    asm("v_pk_fma_f32 %0, %1, %2, %0 op_sel:[0,0,0] op_sel_hi:[0,1,1]"        \
        : "+v"(a) : "v"(w2), "v"(xp))
// a += bcast(w2.hi) * xp
#define PK_HI(a, w2, xp)                                                      \
    asm("v_pk_fma_f32 %0, %1, %2, %0 op_sel:[1,0,0] op_sel_hi:[1,1,1]"        \
        : "+v"(a) : "v"(w2), "v"(xp))

constexpr int TSTEPS = 8;
constexpr int BK     = 16;
constexpr int TILE_M = 64;    // 8 batches * 8 timesteps
constexpr int TILE_NP= 256;   // panel-kernel tile: 4 waves x 64 cols
constexpr int TILE_N = 128;   // fallback-kernel tile
constexpr int KC     = 384;   // OpenBLAS SGEMM_DEFAULT_Q on x86-64

// ---------------------------------------------------------------- phase 1 --
__global__ __launch_bounds__(256, 2)
void spike_panel_gemm(const float* __restrict__ x,
                      const float* __restrict__ w,
                      float* __restrict__ panels,   // ws: panels 0..np-2, NW cols
                      float* __restrict__ out,      // last panel, spike layout
                      int slice0, int NW,
                      int B, int IN, int OUT, int npanels)
{
    // x: k-major double buffer (reg-staged, stride 68 == 4 mod 32: free)
    __shared__ float xs[2][BK][TILE_M + 4];
    // W: DMA-staged, k-chunked linear layout. float offset of (col c,
    // quarter p) = c*16 + p*4; position p holds SOURCE k-quarter p^((c>>2)&3).
    __shared__ float wsh[2][TILE_NP * BK];

    const int tid  = threadIdx.x;
    const int lane = tid & 63;
    const int wv   = tid >> 6;       // wave 0..3 -> col strip [64wv, 64wv+64)
    const int rg   = lane >> 3;      // row octet -> batch within tile
    const int cg   = lane & 7;       // col quad index
    const int cg3  = cg & 3;
    const int clo  = wv * 64 + cg * 4;   // cols clo..+3 and clo+32..+35

    const int m0 = blockIdx.y * TILE_M;
    const int n0 = slice0 + blockIdx.x * TILE_NP;
    const int p  = blockIdx.z;
    const int ks = p * KC;
    const int ke = (ks + KC < IN) ? (ks + KC) : IN;

    // accp[tr][cc]: v2f = {t=2tr, t=2tr+1}; cc 0..3 -> cols clo+cc,
    // cc 4..7 -> cols clo+32+(cc-4)
    v2f accp[4][8];
    #pragma unroll
    for (int tr = 0; tr < 4; ++tr)
        #pragma unroll
        for (int c = 0; c < 8; ++c) accp[tr][c] = (v2f){0.f, 0.f};

    // ---- x staging mapping (reg round-trip, as r13) ----
    const int sr = tid >> 2;         // 0..63
    const int sk = (tid & 3) * 4;    // 0,4,8,12
    const float* xrow = x + (size_t)(m0 + sr) * IN + sk;

    // ---- W DMA source pointers (pre-swizzled k-quarter) ----
    // chunk ci = wv*4+q stages cols ci*16..+15, dest = &wsh[buf][ci*256],
    // lane l holds col c = ci*16 + (l>>2) at position p = l&3, whose source
    // k-quarter is (l&3) ^ ((l>>4)&3)  [== p ^ ((c>>2)&3)].
    const int kqs = ((lane & 3) ^ ((lane >> 4) & 3)) * 4;
    const float* wdma[4];
    #pragma unroll
    for (int q = 0; q < 4; ++q) {
        const int c = (wv * 4 + q) * 16 + (lane >> 2);
        wdma[q] = w + (size_t)(n0 + c) * IN + ks + kqs;
    }

    const int nsteps = (ke - ks) / BK;

    // prologue: DMA W step0 -> buf0; stage x step0 -> buf0
    #pragma unroll
    for (int q = 0; q < 4; ++q) {
        __builtin_amdgcn_global_load_lds(
            (const __attribute__((address_space(1))) void*)wdma[q],
            (__attribute__((address_space(3))) void*)&wsh[0][(wv*4 + q) * 256],
            16, 0, 0);
        wdma[q] += BK;
    }
    {
        const float4 xv0 = *(const float4*)(xrow + ks);
        xs[0][sk+0][sr] = xv0.x;  xs[0][sk+1][sr] = xv0.y;
        xs[0][sk+2][sr] = xv0.z;  xs[0][sk+3][sr] = xv0.w;
    }

    for (int s = 0; s < nsteps; ++s) {
        const int cur = s & 1;
        __syncthreads();   // drains W DMA (vmcnt) + x ds_writes (lgkmcnt)

        const bool hn = (s + 1) < nsteps;
        float4 xv;
        if (hn) {
            // DMA next W tile into the other buffer (everyone passed the
            // barrier, so nobody still reads it)
            #pragma unroll
            for (int q = 0; q < 4; ++q) {
                __builtin_amdgcn_global_load_lds(
                    (const __attribute__((address_space(1))) void*)wdma[q],
                    (__attribute__((address_space(3))) void*)
                        &wsh[cur ^ 1][(wv*4 + q) * 256],
                    16, 0, 0);
                wdma[q] += BK;
            }
            xv = *(const float4*)(xrow + ks + (s + 1) * BK);
        }

        // ---- compute 16 k from xs[cur], wsh[cur] ----
        #pragma unroll
        for (int kq = 0; kq < 4; ++kq) {
            const int woff = ((kq ^ cg3) << 2);
            float4 wq0[4], wq1[4];
            #pragma unroll
            for (int j = 0; j < 4; ++j) {
                wq0[j] = *(const float4*)&wsh[cur][(clo + j) * 16 + woff];
                wq1[j] = *(const float4*)&wsh[cur][(clo + 32 + j) * 16 + woff];
            }
            #pragma unroll
            for (int k2 = 0; k2 < 4; ++k2) {
                const int k = kq * 4 + k2;
                const float4 xa = *(const float4*)&xs[cur][k][rg * 8];
                const float4 xb = *(const float4*)&xs[cur][k][rg * 8 + 4];
                v2f xp[4];
                xp[0] = (v2f){xa.x, xa.y}; xp[1] = (v2f){xa.z, xa.w};
                xp[2] = (v2f){xb.x, xb.y}; xp[3] = (v2f){xb.z, xb.w};
                #pragma unroll
                for (int j = 0; j < 4; ++j) {
                    const v2f* w0 = (const v2f*)&wq0[j];
                    const v2f* w1 = (const v2f*)&wq1[j];
                    #pragma unroll
                    for (int tr = 0; tr < 4; ++tr) {
                        if (k2 == 0) { PK_LO(accp[tr][j],     w0[0], xp[tr]);
                                       PK_LO(accp[tr][4 + j], w1[0], xp[tr]); }
                        if (k2 == 1) { PK_HI(accp[tr][j],     w0[0], xp[tr]);
                                       PK_HI(accp[tr][4 + j], w1[0], xp[tr]); }
                        if (k2 == 2) { PK_LO(accp[tr][j],     w0[1], xp[tr]);
                                       PK_LO(accp[tr][4 + j], w1[1], xp[tr]); }
                        if (k2 == 3) { PK_HI(accp[tr][j],     w0[1], xp[tr]);
                                       PK_HI(accp[tr][4 + j], w1[1], xp[tr]); }
                    }
                }
            }
        }

        if (hn) {
            const int nb = cur ^ 1;
            xs[nb][sk+0][sr] = xv.x;  xs[nb][sk+1][sr] = xv.y;
            xs[nb][sk+2][sr] = xv.z;  xs[nb][sk+3][sr] = xv.w;
        }
    }

    // ---- store panel ----
    const int bg = blockIdx.y * 8 + rg;            // global batch index
    const int cs = blockIdx.x * TILE_NP + clo;     // col within slice
    if (p < npanels - 1) {
        float* pb = panels + ((size_t)p * B * TSTEPS) * NW;
        #pragma unroll
        for (int t = 0; t < TSTEPS; ++t) {
            const int tr = t >> 1;
            float4 lo, hi;
            if (t & 1) {
                lo = (float4){accp[tr][0].y, accp[tr][1].y,
                              accp[tr][2].y, accp[tr][3].y};
                hi = (float4){accp[tr][4].y, accp[tr][5].y,
                              accp[tr][6].y, accp[tr][7].y};
            } else {
                lo = (float4){accp[tr][0].x, accp[tr][1].x,
                              accp[tr][2].x, accp[tr][3].x};
                hi = (float4){accp[tr][4].x, accp[tr][5].x,
                              accp[tr][6].x, accp[tr][7].x};
            }
            const int m = bg * TSTEPS + t;
            *(float4*)(pb + (size_t)m * NW + cs)      = lo;
            *(float4*)(pb + (size_t)m * NW + cs + 32) = hi;
        }
    } else {
        // last panel -> out with SPIKE row mapping (t*B + b)
        const int o0 = n0 + clo;
        #pragma unroll
        for (int t = 0; t < TSTEPS; ++t) {
            const int tr = t >> 1;
            float4 lo, hi;
            if (t & 1) {
                lo = (float4){accp[tr][0].y, accp[tr][1].y,
                              accp[tr][2].y, accp[tr][3].y};
                hi = (float4){accp[tr][4].y, accp[tr][5].y,
                              accp[tr][6].y, accp[tr][7].y};
            } else {
                lo = (float4){accp[tr][0].x, accp[tr][1].x,
                              accp[tr][2].x, accp[tr][3].x};
                hi = (float4){accp[tr][4].x, accp[tr][5].x,
                              accp[tr][6].x, accp[tr][7].x};
            }
            float* op = out + ((size_t)t * B + bg) * OUT + o0;
            *(float4*)op        = lo;
            *(float4*)(op + 32) = hi;
        }
    }
}

// ---------------------------------------------------------------- phase 2 --
__global__ __launch_bounds__(256)
void spike_fold_scan(const float* __restrict__ panels,
                     const float* __restrict__ bias,
                     float* __restrict__ out,
                     int slice0, int NW,
                     int B, int OUT, int npanels)
{
    const int b = blockIdx.y;
    const size_t psz = (size_t)B * TSTEPS * NW;
    const int nc4 = NW / 4;

    for (int c4 = blockIdx.x * 256 + threadIdx.x; c4 < nc4;
         c4 += gridDim.x * 256) {
        const int cs   = c4 * 4;          // col within slice
        const int gcol = slice0 + cs;     // global col

        // v = panel0; v += panel1 ... += panel(np-2)  (exact BLAS order)
        float4 v[TSTEPS];
        #pragma unroll
        for (int t = 0; t < TSTEPS; ++t)
            v[t] = *(const float4*)(panels + (size_t)(b*TSTEPS + t) * NW + cs);
        for (int p = 1; p < npanels - 1; ++p) {
            const float* pb = panels + (size_t)p * psz;
            #pragma unroll
            for (int t = 0; t < TSTEPS; ++t) {
                const float4 u = *(const float4*)(pb + (size_t)(b*TSTEPS + t) * NW + cs);
                v[t].x += u.x; v[t].y += u.y; v[t].z += u.z; v[t].w += u.w;
            }
        }
        // last panel from out (spike layout, owned by this thread)
        #pragma unroll
        for (int t = 0; t < TSTEPS; ++t) {
            const float4 u = *(const float4*)(out + ((size_t)t * B + b) * OUT + gcol);
            v[t].x += u.x; v[t].y += u.y; v[t].z += u.z; v[t].w += u.w;
        }

        const float4 bb = *(const float4*)(bias + gcol);
        float memb[4] = {0.f, 0.f, 0.f, 0.f};
        #pragma unroll
        for (int t = 0; t < TSTEPS; ++t) {
            float pre[4] = {v[t].x + bb.x, v[t].y + bb.y,
                            v[t].z + bb.z, v[t].w + bb.w};
            float4 sp;
            float* spp = (float*)&sp;
            #pragma unroll
            for (int c = 0; c < 4; ++c) {
                memb[c] += pre[c];                       // VTHR = 1.0 (exact)
                float s = (memb[c] > 1.0f) ? 1.0f : 0.0f;
                memb[c] *= (1.0f - s);                   // reset to zero
                spp[c] = s;
            }
            *(float4*)(out + ((size_t)t * B + b) * OUT + gcol) = sp;
        }
    }
}

// ------------------------------------------------- fallback: r3 (verified) --
__global__ __launch_bounds__(256, 4)
void spike_linear_f32seq(const float* __restrict__ x,
                         const float* __restrict__ w,
                         const float* __restrict__ bias,
                         float* __restrict__ out,
                         int B, int IN, int OUT)
{
    __shared__ float xs[BK][TILE_M + 4];
    __shared__ float ws[BK][TILE_N + 4];

    const int tid = threadIdx.x;
    const int tx  = tid & 31;
    const int ty  = tid >> 5;

    const int m0 = blockIdx.y * TILE_M;
    const int n0 = blockIdx.x * TILE_N;

    float acc_tot[TSTEPS][4];
    float acc_blk[TSTEPS][4];
    #pragma unroll
    for (int t = 0; t < TSTEPS; ++t)
        #pragma unroll
        for (int c = 0; c < 4; ++c) { acc_tot[t][c] = 0.f; acc_blk[t][c] = 0.f; }

    const int sr = tid >> 2;
    const int sk = (tid & 3) * 4;

    const float* xrow  = x + (size_t)(m0 + sr) * IN + sk;
    const float* wrow0 = w + (size_t)(n0 + sr) * IN + sk;
    const float* wrow1 = w + (size_t)(n0 + 64 + sr) * IN + sk;

    for (int kk = 0; kk < IN; kk += BK) {
        if (kk > 0 && (kk % KC) == 0) {
            #pragma unroll
            for (int t = 0; t < TSTEPS; ++t)
                #pragma unroll
                for (int c = 0; c < 4; ++c) {
                    acc_tot[t][c] += acc_blk[t][c];
                    acc_blk[t][c] = 0.f;
                }
        }
        const float4 xv  = *(const float4*)(xrow  + kk);
        const float4 wv0 = *(const float4*)(wrow0 + kk);
        const float4 wv1 = *(const float4*)(wrow1 + kk);
        __syncthreads();
        xs[sk+0][sr] = xv.x;  xs[sk+1][sr] = xv.y;
        xs[sk+2][sr] = xv.z;  xs[sk+3][sr] = xv.w;
        ws[sk+0][sr]    = wv0.x; ws[sk+1][sr]    = wv0.y;
        ws[sk+2][sr]    = wv0.z; ws[sk+3][sr]    = wv0.w;
        ws[sk+0][sr+64] = wv1.x; ws[sk+1][sr+64] = wv1.y;
        ws[sk+2][sr+64] = wv1.z; ws[sk+3][sr+64] = wv1.w;
        __syncthreads();

        #pragma unroll
        for (int k = 0; k < BK; ++k) {
            float xr[TSTEPS];
            *(float4*)&xr[0] = *(const float4*)&xs[k][ty*8];
            *(float4*)&xr[4] = *(const float4*)&xs[k][ty*8 + 4];
            float wr[4];
            *(float4*)&wr[0] = *(const float4*)&ws[k][tx*4];
            #pragma unroll
            for (int t = 0; t < TSTEPS; ++t)
                #pragma unroll
                for (int c = 0; c < 4; ++c)
                    acc_blk[t][c] = fmaf(xr[t], wr[c], acc_blk[t][c]);
        }
    }
    #pragma unroll
    for (int t = 0; t < TSTEPS; ++t)
        #pragma unroll
        for (int c = 0; c < 4; ++c)
            acc_tot[t][c] += acc_blk[t][c];

    const int bg = blockIdx.y * 8 + ty;
    const int o0 = n0 + tx * 4;
    const float4 bv = *(const float4*)(bias + o0);
    const float bb[4] = {bv.x, bv.y, bv.z, bv.w};
    float memb[4] = {0.f, 0.f, 0.f, 0.f};
    #pragma unroll
    for (int t = 0; t < TSTEPS; ++t) {
        float4 sp;
        float* spp = (float*)&sp;
        #pragma unroll
        for (int c = 0; c < 4; ++c) {
            float pre = acc_tot[t][c] + bb[c];
            memb[c] += pre;
            float s = (memb[c] > 1.0f) ? 1.0f : 0.0f;
            memb[c] *= (1.0f - s);
            spp[c] = s;
        }
        *(float4*)(out + ((size_t)t * B + bg) * OUT + o0) = sp;
    }
}

extern "C" void kernel_launch(void* const* d_in, const int* in_sizes, int n_in,
                              void* d_out, int out_size, void* d_ws, size_t ws_size,
                              hipStream_t stream)
{
    const float* x    = (const float*)d_in[0];
    const float* w    = (const float*)d_in[1];
    const float* bias = (const float*)d_in[2];
    float* out = (float*)d_out;

    const int OUT = in_sizes[2];            // 4096
    const int IN  = in_sizes[1] / OUT;      // 4096
    const int BT  = in_sizes[0] / IN;       // 2048
    const int B   = BT / TSTEPS;            // 256

    const int npanels = (IN + KC - 1) / KC; // 11

    // pick the widest column slice whose panel storage fits ws
    int NW = 0;
    for (int cand = 4096; cand >= 256; cand >>= 1) {
        if ((OUT % cand) == 0 &&
            (size_t)(npanels - 1) * BT * cand * sizeof(float) <= ws_size) {
            NW = cand;
            break;
        }
    }

    if (NW >= 256 && npanels >= 2) {
        float* panels = (float*)d_ws;
        const int nslices = OUT / NW;
        for (int s = 0; s < nslices; ++s) {
            const int slice0 = s * NW;
            dim3 g1(NW / TILE_NP, BT / TILE_M, npanels);
            spike_panel_gemm<<<g1, 256, 0, stream>>>(x, w, panels, out,
                                                     slice0, NW, B, IN, OUT,
                                                     npanels);
            int gx = NW / 1024; if (gx < 1) gx = 1;
            dim3 g2(gx, B);
            spike_fold_scan<<<g2, 256, 0, stream>>>(panels, bias, out,
                                                    slice0, NW, B, OUT,
                                                    npanels);
        }
    } else {
        dim3 grid(OUT / TILE_N, BT / TILE_M);          // (32, 32)
        spike_linear_f32seq<<<grid, 256, 0, stream>>>(x, w, bias, out, B, IN, OUT);
    }
}